// Round 3
// baseline (482.568 us; speedup 1.0000x reference)
//
#include <hip/hip_runtime.h>

// TemplatePointwiseAttention, MI355X/gfx950.
// Folded-weight formulation: G = Z @ Abar (MFMA), 4-way softmax, OUT = S @ Mbar.
// R3: persistent blocks, NPB=256 (exactly 1/CU), NT=18 tiles of 32 pairs.
// Key change vs R2: __syncthreads (which drains vmcnt(0) -> memory system idles
// every phase) replaced by raw {s_waitcnt lgkmcnt(0); s_barrier}. t2d/z loads
// for tile i+1 are issued at the START of X(i) and consumed (reg->LDS) at the
// START of X(i+1): ~4k cycles in flight, crossing both barriers, so HBM stays
// busy during the attention phase. cvt_pk_bf16_f32 halves conversion VALU.

#define R_    384
#define P_    (R_ * R_)      // 147456 residue pairs
#define PB    32             // pairs per tile
#define NPB   256            // persistent blocks = CUs
#define NT_   18             // (P_/PB)/NPB

typedef __attribute__((ext_vector_type(8))) short  short8;   // 8 x bf16 MFMA frag
typedef __attribute__((ext_vector_type(4))) float  f32x4;    // MFMA accumulator

union S8U { short8 s8; unsigned u[4]; };

__device__ __forceinline__ unsigned short f2bf(float f) {
  unsigned u = __float_as_uint(f);
  unsigned r = ((u >> 16) & 1u) + 0x7FFFu;   // RNE
  return (unsigned short)((u + r) >> 16);
}
__device__ __forceinline__ float bf2f(unsigned short s) {
  return __uint_as_float(((unsigned)s) << 16);
}
__device__ __forceinline__ unsigned cvtpk(float lo, float hi) {
  unsigned d;
  asm("v_cvt_pk_bf16_f32 %0, %1, %2" : "=v"(d) : "v"(lo), "v"(hi));
  return d;
}
// LDS layout for [p][c] tiles (p<32, c<256), bf16, pitch 256, XOR-swizzled in
// 16B blocks (c>>3 ^ p&31).
__device__ __forceinline__ int swz(int p, int c) {
  return p * 256 + ((((c >> 3) ^ (p & 31)) << 3) | (c & 7));
}
// Raw barrier: LDS drain only — prefetch VMEM loads stay in flight (T3/T4).
#define BAR() do { \
    asm volatile("s_waitcnt lgkmcnt(0)\ns_barrier" ::: "memory"); \
    __builtin_amdgcn_sched_barrier(0); \
  } while (0)

// ---- K0: fold weights into AbarT[n=256][i=128], MbarT[o=128][k=256] (bf16) ----
__global__ void prep_kernel(const float* __restrict__ Wq, const float* __restrict__ Wk,
                            const float* __restrict__ Wv, const float* __restrict__ Wo,
                            unsigned short* __restrict__ AbarT,
                            unsigned short* __restrict__ MbarT) {
  int tid = blockIdx.x * blockDim.x + threadIdx.x;   // 65536 threads
  if (tid < 256 * 128) {
    int n = tid >> 7, i = tid & 127;
    int h = n >> 6, j = n & 63;
    const float* wq = Wq + i * 256 + h * 64;
    const float* wk = Wk + j * 256 + h * 64;
    float acc = 0.f;
#pragma unroll 8
    for (int c = 0; c < 64; ++c) acc += wq[c] * wk[c];
    AbarT[n * 128 + i] = f2bf(acc * 0.125f);         // 1/sqrt(64) folded in
  } else {
    int t2 = tid - 256 * 128;
    int o = t2 >> 8, k = t2 & 255;
    int h = k >> 6, j = k & 63;
    const float* wv = Wv + j * 256 + h * 64;
    const float* wo = Wo + (h * 64) * 128 + o;
    float acc = 0.f;
#pragma unroll 8
    for (int c = 0; c < 64; ++c) acc += wv[c] * wo[c * 128];
    MbarT[o * 256 + k] = f2bf(acc);
  }
}

// ---- persistent fused kernel ----
__global__ __launch_bounds__(512, 2) void attn_kernel(
    const float* __restrict__ z2d, const float* __restrict__ t2d,
    const unsigned short* __restrict__ AbarT, const unsigned short* __restrict__ MbarT,
    const float* __restrict__ bo, float* __restrict__ out) {
  extern __shared__ unsigned short smem[];
  unsigned short* sAbar = smem;            // [256][128] swizzled, 64 KB
  unsigned short* sT    = smem + 32768;    // 2 x [32][256] swizzled, 2x16 KB
  unsigned short* sG    = smem + 49152;    // 2 x [32][256] swizzled, 2x16 KB

  const int tid  = threadIdx.x;
  const int wv_  = tid >> 6;
  const int lane = tid & 63;
  const int l = lane & 15;     // MFMA: A row / B col / D col
  const int q = lane >> 4;     // MFMA quad
  const int mt = wv_ & 1;      // m-tile
  const int ng = wv_ >> 1;     // n-group

  // ---- tile-invariant per-thread geometry ----
  int sOffS[4], sOffD[4];      // t2d staging: src float-offset, sT elem-offset
#pragma unroll
  for (int k2 = 0; k2 < 4; ++k2) {
    int f = k2 * 512 + tid, t = f >> 9, rr = f & 511;
    int p2 = rr >> 4, j4 = (rr & 15) << 2;
    sOffS[k2] = t * (P_ * 64) + p2 * 64 + j4;
    sOffD[k2] = swz(p2, t * 64 + j4);
  }
  const int zoff = (mt * 16 + l) * 128;    // z2d row offset (+P0*128)
  const int p2g  = mt * 16 + l;            // GEMM2 A-row
  // attention geometry
  const int ap = tid >> 4, asub = tid & 15;
  const int ah = asub >> 2, au = asub & 3;
  const int aoG0 = swz(ap, ah * 64 + au * 16);
  const int aoG1 = swz(ap, ah * 64 + au * 16 + 8);
  int aoK[4][2];
#pragma unroll
  for (int t = 0; t < 4; ++t) {
    aoK[t][0] = swz(ap, t * 64 + au * 16);
    aoK[t][1] = swz(ap, t * 64 + au * 16 + 8);
  }

  // ---- prologue: Abar -> LDS (swizzled) ----
#pragma unroll
  for (int k2 = 0; k2 < 8; ++k2) {
    int id = k2 * 512 + tid, n = id >> 4, blk = id & 15;
    short8 v = *(const short8*)(AbarT + n * 128 + blk * 8);
    *(short8*)(sAbar + n * 128 + ((blk ^ (n & 15)) << 3)) = v;
  }
  // ---- Mbar -> regs (wave-sliced: 2 o-tiles x 8 kk) ----
  short8 mb0[8], mb1[8];
#pragma unroll
  for (int kk = 0; kk < 8; ++kk) {
    mb0[kk] = *(const short8*)(MbarT + (size_t)((ng * 2)     * 16 + l) * 256 + kk * 32 + q * 8);
    mb1[kk] = *(const short8*)(MbarT + (size_t)((ng * 2 + 1) * 16 + l) * 256 + kk * 32 + q * 8);
  }
  const float bo0 = bo[(ng * 2) * 16 + l];
  const float bo1 = bo[(ng * 2 + 1) * 16 + l];

  // ---- issue tile-0 loads (issued AFTER sAbar loads so the staging vmcnt
  //      waits don't force them; they ride across the prologue barrier) ----
  float4 st0, st1, st2, st3;
  float4 zpA[8], zpB[8];
  {
    const size_t P00 = (size_t)blockIdx.x * PB;
    const float* tb = t2d + P00 * 64;
    st0 = *(const float4*)(tb + sOffS[0]);
    st1 = *(const float4*)(tb + sOffS[1]);
    st2 = *(const float4*)(tb + sOffS[2]);
    st3 = *(const float4*)(tb + sOffS[3]);
    const float* zr = z2d + P00 * 128 + zoff;
#pragma unroll
    for (int kk = 0; kk < 4; ++kk) {
      zpA[2 * kk]     = *(const float4*)(zr + kk * 32 + q * 8);
      zpA[2 * kk + 1] = *(const float4*)(zr + kk * 32 + q * 8 + 4);
    }
  }
  BAR();   // sAbar visible; tile-0 loads still in flight

  // GEMM2 for tile (it-1): reads S from sGp, Mbar regs, stores to out.
  auto gemm2 = [&](const unsigned short* sGp, size_t P0p) {
    f32x4 a20 = f32x4{0.f, 0.f, 0.f, 0.f};
    f32x4 a21 = f32x4{0.f, 0.f, 0.f, 0.f};
#pragma unroll
    for (int kk = 0; kk < 8; ++kk) {
      short8 af2 = *(const short8*)(sGp + p2g * 256 + (((kk * 4 + q) ^ (p2g & 31)) << 3));
      a20 = __builtin_amdgcn_mfma_f32_16x16x32_bf16(af2, mb0[kk], a20, 0, 0, 0);
      a21 = __builtin_amdgcn_mfma_f32_16x16x32_bf16(af2, mb1[kk], a21, 0, 0, 0);
    }
    const size_t rb = (P0p + (size_t)(mt * 16 + q * 4)) * 128;
#pragma unroll
    for (int r = 0; r < 4; ++r) {
      out[rb + r * 128 + ng * 32 + l]      = a20[r] + bo0;
      out[rb + r * 128 + ng * 32 + 16 + l] = a21[r] + bo1;
    }
  };

  // attention on tile buffers (sTc, sGc); S overwrites this thread's G slice.
  auto attention = [&](const unsigned short* sTc, unsigned short* sGc) {
    short8 g0 = *(const short8*)(sGc + aoG0);
    short8 g1 = *(const short8*)(sGc + aoG1);
    short8 kc00 = *(const short8*)(sTc + aoK[0][0]);
    short8 kc01 = *(const short8*)(sTc + aoK[0][1]);
    short8 kc10 = *(const short8*)(sTc + aoK[1][0]);
    short8 kc11 = *(const short8*)(sTc + aoK[1][1]);
    short8 kc20 = *(const short8*)(sTc + aoK[2][0]);
    short8 kc21 = *(const short8*)(sTc + aoK[2][1]);
    short8 kc30 = *(const short8*)(sTc + aoK[3][0]);
    short8 kc31 = *(const short8*)(sTc + aoK[3][1]);
    float lg0 = 0.f, lg1 = 0.f, lg2 = 0.f, lg3 = 0.f;
#pragma unroll
    for (int e = 0; e < 8; ++e) {
      const float ga = bf2f((unsigned short)g0[e]);
      const float gb = bf2f((unsigned short)g1[e]);
      lg0 += ga * bf2f((unsigned short)kc00[e]) + gb * bf2f((unsigned short)kc01[e]);
      lg1 += ga * bf2f((unsigned short)kc10[e]) + gb * bf2f((unsigned short)kc11[e]);
      lg2 += ga * bf2f((unsigned short)kc20[e]) + gb * bf2f((unsigned short)kc21[e]);
      lg3 += ga * bf2f((unsigned short)kc30[e]) + gb * bf2f((unsigned short)kc31[e]);
    }
    lg0 += __shfl_xor(lg0, 1); lg0 += __shfl_xor(lg0, 2);
    lg1 += __shfl_xor(lg1, 1); lg1 += __shfl_xor(lg1, 2);
    lg2 += __shfl_xor(lg2, 1); lg2 += __shfl_xor(lg2, 2);
    lg3 += __shfl_xor(lg3, 1); lg3 += __shfl_xor(lg3, 2);
    const float mx = fmaxf(fmaxf(lg0, lg1), fmaxf(lg2, lg3));
    float e0 = __expf(lg0 - mx), e1 = __expf(lg1 - mx);
    float e2 = __expf(lg2 - mx), e3 = __expf(lg3 - mx);
    const float inv = 1.f / (e0 + e1 + e2 + e3);
    e0 *= inv; e1 *= inv; e2 *= inv; e3 *= inv;
    S8U sv;
#pragma unroll
    for (int j2 = 0; j2 < 4; ++j2) {
      float s0 = e0 * bf2f((unsigned short)kc00[2 * j2])     + e1 * bf2f((unsigned short)kc10[2 * j2])
               + e2 * bf2f((unsigned short)kc20[2 * j2])     + e3 * bf2f((unsigned short)kc30[2 * j2]);
      float s1 = e0 * bf2f((unsigned short)kc00[2 * j2 + 1]) + e1 * bf2f((unsigned short)kc10[2 * j2 + 1])
               + e2 * bf2f((unsigned short)kc20[2 * j2 + 1]) + e3 * bf2f((unsigned short)kc30[2 * j2 + 1]);
      sv.u[j2] = cvtpk(s0, s1);
    }
    *(short8*)(sGc + aoG0) = sv.s8;
#pragma unroll
    for (int j2 = 0; j2 < 4; ++j2) {
      float s0 = e0 * bf2f((unsigned short)kc01[2 * j2])     + e1 * bf2f((unsigned short)kc11[2 * j2])
               + e2 * bf2f((unsigned short)kc21[2 * j2])     + e3 * bf2f((unsigned short)kc31[2 * j2]);
      float s1 = e0 * bf2f((unsigned short)kc01[2 * j2 + 1]) + e1 * bf2f((unsigned short)kc11[2 * j2 + 1])
               + e2 * bf2f((unsigned short)kc21[2 * j2 + 1]) + e3 * bf2f((unsigned short)kc31[2 * j2 + 1]);
      sv.u[j2] = cvtpk(s0, s1);
    }
    *(short8*)(sGc + aoG1) = sv.s8;
  };

#define HALF_BODY(IT_, CUR_, ZPC, ZPN, DO_G2, DO_PF)                           \
  {                                                                            \
    const size_t P0 = (size_t)blockIdx.x * PB + (size_t)(IT_) * (NPB * PB);    \
    unsigned short* sTc = sT + (CUR_) * 8192;                                  \
    unsigned short* sGc = sG + (CUR_) * 8192;                                  \
    const unsigned short* sGp = sG + (1 - (CUR_)) * 8192;                      \
    /* (a) staged tkv regs (loaded one iteration ago) -> sT[cur] */            \
    { uint2 w;                                                                 \
      w.x = cvtpk(st0.x, st0.y); w.y = cvtpk(st0.z, st0.w);                    \
      *(uint2*)(sTc + sOffD[0]) = w;                                           \
      w.x = cvtpk(st1.x, st1.y); w.y = cvtpk(st1.z, st1.w);                    \
      *(uint2*)(sTc + sOffD[1]) = w;                                           \
      w.x = cvtpk(st2.x, st2.y); w.y = cvtpk(st2.z, st2.w);                    \
      *(uint2*)(sTc + sOffD[2]) = w;                                           \
      w.x = cvtpk(st3.x, st3.y); w.y = cvtpk(st3.z, st3.w);                    \
      *(uint2*)(sTc + sOffD[3]) = w; }                                         \
    /* (b,c) issue tile IT+1 loads; consumed at next X -> in flight across Y */\
    if (DO_PF) {                                                               \
      const float* tb = t2d + (P0 + NPB * PB) * 64;                            \
      st0 = *(const float4*)(tb + sOffS[0]);                                   \
      st1 = *(const float4*)(tb + sOffS[1]);                                   \
      st2 = *(const float4*)(tb + sOffS[2]);                                   \
      st3 = *(const float4*)(tb + sOffS[3]);                                   \
      const float* zr = z2d + (P0 + NPB * PB) * 128 + zoff;                    \
      _Pragma("unroll")                                                        \
      for (int kk = 0; kk < 4; ++kk) {                                         \
        ZPN[2 * kk]     = *(const float4*)(zr + kk * 32 + q * 8);              \
        ZPN[2 * kk + 1] = *(const float4*)(zr + kk * 32 + q * 8 + 4);          \
      }                                                                        \
    }                                                                          \
    /* (d) GEMM2 for tile IT-1 */                                              \
    if (DO_G2) gemm2(sGp, P0 - (size_t)(NPB * PB));                            \
    /* (e) GEMM1 tile IT: Z(regs) @ Abar(LDS) -> G -> sG[cur] */               \
    {                                                                          \
      f32x4 a1[4];                                                             \
      _Pragma("unroll")                                                        \
      for (int i = 0; i < 4; ++i) a1[i] = f32x4{0.f, 0.f, 0.f, 0.f};           \
      _Pragma("unroll")                                                        \
      for (int kk = 0; kk < 4; ++kk) {                                         \
        S8U af;                                                                \
        af.u[0] = cvtpk(ZPC[2 * kk].x,     ZPC[2 * kk].y);                     \
        af.u[1] = cvtpk(ZPC[2 * kk].z,     ZPC[2 * kk].w);                     \
        af.u[2] = cvtpk(ZPC[2 * kk + 1].x, ZPC[2 * kk + 1].y);                 \
        af.u[3] = cvtpk(ZPC[2 * kk + 1].z, ZPC[2 * kk + 1].w);                 \
        _Pragma("unroll")                                                      \
        for (int i = 0; i < 4; ++i) {                                          \
          const int n = (ng * 4 + i) * 16 + l;                                 \
          short8 bf = *(const short8*)(sAbar + n * 128 + (((kk * 4 + q) ^ l) << 3)); \
          a1[i] = __builtin_amdgcn_mfma_f32_16x16x32_bf16(af.s8, bf, a1[i], 0, 0, 0); \
        }                                                                      \
      }                                                                        \
      _Pragma("unroll")                                                        \
      for (int i = 0; i < 4; ++i) {                                            \
        const int c = (ng * 4 + i) * 16 + l;                                   \
        _Pragma("unroll")                                                      \
        for (int r = 0; r < 4; ++r) {                                          \
          const int p2 = mt * 16 + q * 4 + r;                                  \
          sGc[swz(p2, c)] = f2bf(a1[i][r]);   /* D[m=q*4+r][n=l], m89-verified */ \
        }                                                                      \
      }                                                                        \
    }                                                                          \
    BAR();                                                                     \
    /* (g) attention tile IT */                                                \
    attention(sTc, sGc);                                                       \
    BAR();                                                                     \
  }

#pragma unroll 1
  for (int j = 0; j < NT_ / 2; ++j) {
    const int it0 = 2 * j;
    HALF_BODY(it0,     0, zpA, zpB, (it0 > 0), true);
    HALF_BODY(it0 + 1, 1, zpB, zpA, true,      (j < NT_ / 2 - 1));
  }
#undef HALF_BODY

  // ---- tail: GEMM2 for the last tile (CUR of NT_-1 = 1) ----
  gemm2(sG + 8192, (size_t)blockIdx.x * PB + (size_t)(NT_ - 1) * (NPB * PB));
}

extern "C" void kernel_launch(void* const* d_in, const int* in_sizes, int n_in,
                              void* d_out, int out_size, void* d_ws, size_t ws_size,
                              hipStream_t stream) {
  const float* z2d = (const float*)d_in[0];
  const float* t2d = (const float*)d_in[1];
  const float* Wq  = (const float*)d_in[2];
  const float* Wk  = (const float*)d_in[3];
  const float* Wv  = (const float*)d_in[4];
  const float* Wo  = (const float*)d_in[5];
  const float* bo  = (const float*)d_in[6];

  unsigned short* AbarT = (unsigned short*)d_ws;           // 256*128 bf16 = 64 KB
  unsigned short* MbarT = AbarT + 256 * 128;               // 128*256 bf16 = 64 KB
  float* out = (float*)d_out;

  static bool attr_set = false;
  if (!attr_set) {
    (void)hipFuncSetAttribute((const void*)attn_kernel,
                              hipFuncAttributeMaxDynamicSharedMemorySize, 131072);
    attr_set = true;
  }

  hipLaunchKernelGGL(prep_kernel, dim3(256), dim3(256), 0, stream,
                     Wq, Wk, Wv, Wo, AbarT, MbarT);
  hipLaunchKernelGGL(attn_kernel, dim3(NPB), dim3(512), 131072, stream,
                     z2d, t2d, AbarT, MbarT, bo, out);
}

// Round 4
// 300.518 us; speedup vs baseline: 1.6058x; 1.6058x over previous
//
#include <hip/hip_runtime.h>

// TemplatePointwiseAttention, MI355X/gfx950.
// Folded-weight formulation: G = Z @ Abar (MFMA), 4-way softmax, OUT = S @ Mbar.
// R4: persistent 256 blocks x 512 threads, 18 tiles of 32 pairs.
//  - t2d staged fp32 via global_load_lds (no VGPRs, no conversion VALU),
//    2-slot LDS ring; DMA(k+1) issued at top of X(k), consumed at Y(k+1):
//    in flight across attention -> memory concurrency (R2 was 23% BW from
//    phase-drained bursts; R3's reg-based depth spilled: FETCH +200MB).
//  - Correctness: sched_barrier-pinned order DMA(k) < z(k); GEMM1(k)'s use of
//    z(k) makes the compiler's vmcnt wait retire DMA(k) (in-order vmcnt, m135)
//    before the pre-attention barrier. No manual vmcnt counting.
//  - Raw {lgkmcnt(0); s_barrier} barriers (no vmcnt drain).
//  - K read fp32 in attention; chunk XOR-swizzle applied on the GLOBAL source
//    (LDS linear for DMA, rule 21) -> 2-way banks = free.
// LDS: Abar 64K + sT 2x32K + sG 2x16K = 160 KB exactly (1 block/CU).

#define R_    384
#define P_    (R_ * R_)      // 147456 residue pairs
#define PB    32             // pairs per tile
#define NPB   256            // persistent blocks = CUs
#define NT_   18             // (P_/PB)/NPB

typedef __attribute__((ext_vector_type(8))) short  short8;   // 8 x bf16 MFMA frag
typedef __attribute__((ext_vector_type(4))) float  f32x4;    // MFMA accumulator

union S8U { short8 s8; unsigned u[4]; };

__device__ __forceinline__ unsigned short f2bf(float f) {
  unsigned u = __float_as_uint(f);
  unsigned r = ((u >> 16) & 1u) + 0x7FFFu;   // RNE
  return (unsigned short)((u + r) >> 16);
}
__device__ __forceinline__ float bf2f(unsigned short s) {
  return __uint_as_float(((unsigned)s) << 16);
}
__device__ __forceinline__ unsigned cvtpk(float lo, float hi) {
  unsigned d;
  asm("v_cvt_pk_bf16_f32 %0, %1, %2" : "=v"(d) : "v"(lo), "v"(hi));
  return d;
}
// bf16 LDS tiles [p][c] (p<32, c<256), pitch 256, XOR-swizzled in 16B blocks.
__device__ __forceinline__ int swz(int p, int c) {
  return p * 256 + ((((c >> 3) ^ (p & 31)) << 3) | (c & 7));
}
#define SB() __builtin_amdgcn_sched_barrier(0)
// Raw barrier: LDS drain only — in-flight VMEM (DMA/z prefetch) crosses it.
#define BAR() do { \
    asm volatile("s_waitcnt lgkmcnt(0)\ns_barrier" ::: "memory"); \
    SB(); \
  } while (0)

__device__ __forceinline__ void dma16(const float* g, void* lds) {
  // 16B per lane; LDS dest = wave-uniform base + lane*16 (HW adds lane part).
  __builtin_amdgcn_global_load_lds((const __attribute__((address_space(1))) unsigned*)g,
                                   (__attribute__((address_space(3))) unsigned*)lds,
                                   16, 0, 0);
}

// ---- K0: fold weights into AbarT[n=256][i=128], MbarT[o=128][k=256] (bf16) ----
__global__ void prep_kernel(const float* __restrict__ Wq, const float* __restrict__ Wk,
                            const float* __restrict__ Wv, const float* __restrict__ Wo,
                            unsigned short* __restrict__ AbarT,
                            unsigned short* __restrict__ MbarT) {
  int tid = blockIdx.x * blockDim.x + threadIdx.x;   // 65536 threads
  if (tid < 256 * 128) {
    int n = tid >> 7, i = tid & 127;
    int h = n >> 6, j = n & 63;
    const float* wq = Wq + i * 256 + h * 64;
    const float* wk = Wk + j * 256 + h * 64;
    float acc = 0.f;
#pragma unroll 8
    for (int c = 0; c < 64; ++c) acc += wq[c] * wk[c];
    AbarT[n * 128 + i] = f2bf(acc * 0.125f);         // 1/sqrt(64) folded in
  } else {
    int t2 = tid - 256 * 128;
    int o = t2 >> 8, k = t2 & 255;
    int h = k >> 6, j = k & 63;
    const float* wv = Wv + j * 256 + h * 64;
    const float* wo = Wo + (h * 64) * 128 + o;
    float acc = 0.f;
#pragma unroll 8
    for (int c = 0; c < 64; ++c) acc += wv[c] * wo[c * 128];
    MbarT[o * 256 + k] = f2bf(acc);
  }
}

// ---- persistent fused kernel ----
__global__ __launch_bounds__(512, 2) void attn_kernel(
    const float* __restrict__ z2d, const float* __restrict__ t2d,
    const unsigned short* __restrict__ AbarT, const unsigned short* __restrict__ MbarT,
    const float* __restrict__ bo, float* __restrict__ out) {
  extern __shared__ char smem[];
  unsigned short* sAbar = (unsigned short*)smem;            // 64 KB bf16 swizzled
  float*          sTf   = (float*)(smem + 65536);           // 2 x [4][32][64] fp32
  unsigned short* sG    = (unsigned short*)(smem + 131072); // 2 x [32][256] bf16 swz

  const int tid  = threadIdx.x;
  const int wv_  = tid >> 6;
  const int lane = tid & 63;
  const int l = lane & 15;     // MFMA: A row / B col / D col
  const int q = lane >> 4;     // MFMA quad
  const int mt = wv_ & 1;      // m-tile
  const int ng = wv_ >> 1;     // n-group

  // ---- DMA per-lane geometry: wave wv_ covers rows [wv_*4, wv_*4+4) per t.
  // Content swizzle: LDS chunk-slot cs holds global 16B-chunk cs^(p&3).
  const int dp  = wv_ * 4 + (lane >> 4);                    // pair row in tile
  const int dcf = (((lane & 15) ^ ((lane >> 4) & 3)) << 2); // float offset in row

  // ---- attention geometry: thread = (pair ap, head ah, quarter au) ----
  const int ap = tid >> 4, asub = tid & 15;
  const int ah = asub >> 2, au = asub & 3;
  const int aoG0 = swz(ap, ah * 64 + au * 16);
  const int aoG1 = swz(ap, ah * 64 + au * 16 + 8);
  int aoK[4];                                               // float offsets, + t*2048
#pragma unroll
  for (int j = 0; j < 4; ++j)
    aoK[j] = ap * 64 + ((((au * 4 + j) ^ (ap & 3))) << 2);

  const int p2g = mt * 16 + l;                              // GEMM2 A-row

  // ---- prologue: Abar -> LDS (swizzled) ----
#pragma unroll
  for (int k2 = 0; k2 < 8; ++k2) {
    int id = k2 * 512 + tid, n = id >> 4, blk = id & 15;
    short8 v = *(const short8*)(AbarT + n * 128 + blk * 8);
    *(short8*)(sAbar + n * 128 + ((blk ^ (n & 15)) << 3)) = v;
  }
  // ---- Mbar -> regs (wave-sliced: 2 o-tiles x 8 kk) ----
  short8 mb0[8], mb1[8];
#pragma unroll
  for (int kk = 0; kk < 8; ++kk) {
    mb0[kk] = *(const short8*)(MbarT + (size_t)(ng * 32 + l) * 256 + kk * 32 + q * 8);
    mb1[kk] = *(const short8*)(MbarT + (size_t)(ng * 32 + 16 + l) * 256 + kk * 32 + q * 8);
  }
  const float bo0 = bo[ng * 32 + l];
  const float bo1 = bo[ng * 32 + 16 + l];
  SB();
  // ---- DMA(0) then z(0): order matters — z(0)'s use at X(0) retires DMA(0) ----
  {
    const size_t P00 = (size_t)blockIdx.x * PB;
    char* dst = (char*)sTf + wv_ * 1024;
#pragma unroll
    for (int m = 0; m < 4; ++m)
      dma16(t2d + ((size_t)m * P_ + P00 + dp) * 64 + dcf, dst + m * 8192);
  }
  SB();
  float4 zb[8];
  {
    const float* zr = z2d + ((size_t)blockIdx.x * PB + mt * 16 + l) * 128;
#pragma unroll
    for (int kk = 0; kk < 4; ++kk) {
      zb[2 * kk]     = *(const float4*)(zr + kk * 32 + q * 8);
      zb[2 * kk + 1] = *(const float4*)(zr + kk * 32 + q * 8 + 4);
    }
  }
  BAR();   // sAbar visible; DMA(0)/z(0) in flight

#pragma unroll 1
  for (int k = 0; k < NT_; ++k) {
    const int sl = k & 1;
    const size_t P0 = (size_t)(blockIdx.x + (size_t)k * NPB) * PB;
    const size_t P0n = P0 + (size_t)NPB * PB;

    // ======== phase X ========
    // (1) DMA(k+1) -> sT[sl^1]  (first read at Y(k+1): long in-flight window)
    if (k + 1 < NT_) {
      char* dst = (char*)sTf + (sl ^ 1) * 32768 + wv_ * 1024;
#pragma unroll
      for (int m = 0; m < 4; ++m)
        dma16(t2d + ((size_t)m * P_ + P0n + dp) * 64 + dcf, dst + m * 8192);
    }
    SB();
    // (2) GEMM2 tile k-1: S(sG[sl^1]) @ Mbar(regs) -> out
    if (k > 0) {
      const unsigned short* sGp = sG + (sl ^ 1) * 8192;
      f32x4 a20 = f32x4{0.f, 0.f, 0.f, 0.f};
      f32x4 a21 = f32x4{0.f, 0.f, 0.f, 0.f};
#pragma unroll
      for (int kk = 0; kk < 8; ++kk) {
        short8 af2 = *(const short8*)(sGp + p2g * 256 + (((kk * 4 + q) ^ p2g) << 3));
        a20 = __builtin_amdgcn_mfma_f32_16x16x32_bf16(af2, mb0[kk], a20, 0, 0, 0);
        a21 = __builtin_amdgcn_mfma_f32_16x16x32_bf16(af2, mb1[kk], a21, 0, 0, 0);
      }
      const size_t rb = (P0 - (size_t)NPB * PB + (size_t)(mt * 16 + q * 4)) * 128;
#pragma unroll
      for (int r = 0; r < 4; ++r) {
        out[rb + r * 128 + ng * 32 + l]      = a20[r] + bo0;
        out[rb + r * 128 + ng * 32 + 16 + l] = a21[r] + bo1;
      }
    }
    SB();
    // (3) GEMM1 tile k: af=cvt(zb) — compiler's vmcnt wait here retires z(k)
    //     and (in-order) DMA(k). Then MFMA vs sAbar; G -> sG[sl].
    {
      f32x4 a1[4];
#pragma unroll
      for (int i = 0; i < 4; ++i) a1[i] = f32x4{0.f, 0.f, 0.f, 0.f};
#pragma unroll
      for (int kk = 0; kk < 4; ++kk) {
        S8U af;
        af.u[0] = cvtpk(zb[2 * kk].x,     zb[2 * kk].y);
        af.u[1] = cvtpk(zb[2 * kk].z,     zb[2 * kk].w);
        af.u[2] = cvtpk(zb[2 * kk + 1].x, zb[2 * kk + 1].y);
        af.u[3] = cvtpk(zb[2 * kk + 1].z, zb[2 * kk + 1].w);
#pragma unroll
        for (int i = 0; i < 4; ++i) {
          const int n = (ng * 4 + i) * 16 + l;
          short8 bf = *(const short8*)(sAbar + n * 128 + (((kk * 4 + q) ^ l) << 3));
          a1[i] = __builtin_amdgcn_mfma_f32_16x16x32_bf16(af.s8, bf, a1[i], 0, 0, 0);
        }
      }
      unsigned short* sGc = sG + sl * 8192;
#pragma unroll
      for (int i = 0; i < 4; ++i) {
        const int c = (ng * 4 + i) * 16 + l;
#pragma unroll
        for (int r = 0; r < 4; ++r)
          sGc[swz(mt * 16 + q * 4 + r, c)] = f2bf(a1[i][r]);  // m89-verified D layout
      }
    }
    SB();
    // (4) z(k+1) -> zb (issued last; in flight across Y(k))
    if (k + 1 < NT_) {
      const float* zr = z2d + (P0n + (size_t)(mt * 16 + l)) * 128;
#pragma unroll
      for (int kk = 0; kk < 4; ++kk) {
        zb[2 * kk]     = *(const float4*)(zr + kk * 32 + q * 8);
        zb[2 * kk + 1] = *(const float4*)(zr + kk * 32 + q * 8 + 4);
      }
    }
    SB();
    BAR();

    // ======== phase Y: attention ========
    {
      const float* Kt = sTf + sl * 8192;                // [4][32][64] fp32, chunk-swz
      unsigned short* sGc = sG + sl * 8192;
      short8 g0 = *(const short8*)(sGc + aoG0);
      short8 g1 = *(const short8*)(sGc + aoG1);
      float lg0 = 0.f, lg1 = 0.f, lg2 = 0.f, lg3 = 0.f;
#pragma unroll
      for (int j = 0; j < 4; ++j) {
        const float ga = bf2f((unsigned short)((j < 2) ? g0[4 * j]     : g1[4 * (j - 2)]));
        const float gb = bf2f((unsigned short)((j < 2) ? g0[4 * j + 1] : g1[4 * (j - 2) + 1]));
        const float gc = bf2f((unsigned short)((j < 2) ? g0[4 * j + 2] : g1[4 * (j - 2) + 2]));
        const float gd = bf2f((unsigned short)((j < 2) ? g0[4 * j + 3] : g1[4 * (j - 2) + 3]));
        float4 k0 = *(const float4*)(Kt +        aoK[j]);
        float4 k1 = *(const float4*)(Kt + 2048 + aoK[j]);
        float4 k2 = *(const float4*)(Kt + 4096 + aoK[j]);
        float4 k3 = *(const float4*)(Kt + 6144 + aoK[j]);
        lg0 += ga * k0.x + gb * k0.y + gc * k0.z + gd * k0.w;
        lg1 += ga * k1.x + gb * k1.y + gc * k1.z + gd * k1.w;
        lg2 += ga * k2.x + gb * k2.y + gc * k2.z + gd * k2.w;
        lg3 += ga * k3.x + gb * k3.y + gc * k3.z + gd * k3.w;
      }
      lg0 += __shfl_xor(lg0, 1); lg0 += __shfl_xor(lg0, 2);
      lg1 += __shfl_xor(lg1, 1); lg1 += __shfl_xor(lg1, 2);
      lg2 += __shfl_xor(lg2, 1); lg2 += __shfl_xor(lg2, 2);
      lg3 += __shfl_xor(lg3, 1); lg3 += __shfl_xor(lg3, 2);
      const float mx = fmaxf(fmaxf(lg0, lg1), fmaxf(lg2, lg3));
      float e0 = __expf(lg0 - mx), e1 = __expf(lg1 - mx);
      float e2 = __expf(lg2 - mx), e3 = __expf(lg3 - mx);
      const float inv = 1.f / (e0 + e1 + e2 + e3);
      e0 *= inv; e1 *= inv; e2 *= inv; e3 *= inv;
      // S[ap][ah*64+au*16+j*4 ..+4) = sum_t e_t * K_t  (own slice, in place)
#pragma unroll
      for (int j = 0; j < 4; ++j) {
        float4 k0 = *(const float4*)(Kt +        aoK[j]);
        float4 k1 = *(const float4*)(Kt + 2048 + aoK[j]);
        float4 k2 = *(const float4*)(Kt + 4096 + aoK[j]);
        float4 k3 = *(const float4*)(Kt + 6144 + aoK[j]);
        float s0 = e0 * k0.x + e1 * k1.x + e2 * k2.x + e3 * k3.x;
        float s1 = e0 * k0.y + e1 * k1.y + e2 * k2.y + e3 * k3.y;
        float s2 = e0 * k0.z + e1 * k1.z + e2 * k2.z + e3 * k3.z;
        float s3 = e0 * k0.w + e1 * k1.w + e2 * k2.w + e3 * k3.w;
        uint2 w2; w2.x = cvtpk(s0, s1); w2.y = cvtpk(s2, s3);
        *(uint2*)(sGc + swz(ap, ah * 64 + au * 16 + j * 4)) = w2;   // 8B, aligned
      }
    }
    BAR();
  }

  // ---- tail: GEMM2 for the last tile (sl of NT_-1 = 1) ----
  {
    const unsigned short* sGp = sG + 8192;
    f32x4 a20 = f32x4{0.f, 0.f, 0.f, 0.f};
    f32x4 a21 = f32x4{0.f, 0.f, 0.f, 0.f};
#pragma unroll
    for (int kk = 0; kk < 8; ++kk) {
      short8 af2 = *(const short8*)(sGp + p2g * 256 + (((kk * 4 + q) ^ p2g) << 3));
      a20 = __builtin_amdgcn_mfma_f32_16x16x32_bf16(af2, mb0[kk], a20, 0, 0, 0);
      a21 = __builtin_amdgcn_mfma_f32_16x16x32_bf16(af2, mb1[kk], a21, 0, 0, 0);
    }
    const size_t rb = ((size_t)(blockIdx.x + (size_t)(NT_ - 1) * NPB) * PB
                       + (size_t)(mt * 16 + q * 4)) * 128;
#pragma unroll
    for (int r = 0; r < 4; ++r) {
      out[rb + r * 128 + ng * 32 + l]      = a20[r] + bo0;
      out[rb + r * 128 + ng * 32 + 16 + l] = a21[r] + bo1;
    }
  }
}

extern "C" void kernel_launch(void* const* d_in, const int* in_sizes, int n_in,
                              void* d_out, int out_size, void* d_ws, size_t ws_size,
                              hipStream_t stream) {
  const float* z2d = (const float*)d_in[0];
  const float* t2d = (const float*)d_in[1];
  const float* Wq  = (const float*)d_in[2];
  const float* Wk  = (const float*)d_in[3];
  const float* Wv  = (const float*)d_in[4];
  const float* Wo  = (const float*)d_in[5];
  const float* bo  = (const float*)d_in[6];

  unsigned short* AbarT = (unsigned short*)d_ws;           // 256*128 bf16 = 64 KB
  unsigned short* MbarT = AbarT + 256 * 128;               // 128*256 bf16 = 64 KB
  float* out = (float*)d_out;

  static bool attr_set = false;
  if (!attr_set) {
    (void)hipFuncSetAttribute((const void*)attn_kernel,
                              hipFuncAttributeMaxDynamicSharedMemorySize, 163840);
    attr_set = true;
  }

  hipLaunchKernelGGL(prep_kernel, dim3(256), dim3(256), 0, stream,
                     Wq, Wk, Wv, Wo, AbarT, MbarT);
  hipLaunchKernelGGL(attn_kernel, dim3(NPB), dim3(512), 163840, stream,
                     z2d, t2d, AbarT, MbarT, bo, out);
}